// Round 1
// baseline (606.805 us; speedup 1.0000x reference)
//
#include <hip/hip_runtime.h>
#include <math.h>

#define N_NODES 50000
#define N_EDGES 1200000
#define BATCH   64
#define D       64
#define EPS     1e-12f

// ---------------------------------------------------------------------------
// CSR row offsets from sorted edge_row: row_start[r] = lower_bound(edge_row, r)
// ---------------------------------------------------------------------------
__global__ void k_rowstart(const int* __restrict__ edge_row, int* __restrict__ row_start) {
    int r = blockIdx.x * blockDim.x + threadIdx.x;
    if (r > N_NODES) return;
    int lo = 0, hi = N_EDGES;
    while (lo < hi) {
        int mid = (lo + hi) >> 1;
        if (edge_row[mid] < r) lo = mid + 1; else hi = mid;
    }
    row_start[r] = lo;
}

// ---------------------------------------------------------------------------
// Fused weights: M2 = W2 @ Wl[:64,:], M3 = W3 @ Wl[64:,:]
// grid 64 (k), block 64 (j)
// ---------------------------------------------------------------------------
__global__ void k_fuse(const float* __restrict__ W2, const float* __restrict__ W3,
                       const float* __restrict__ Wl,
                       float* __restrict__ M2, float* __restrict__ M3) {
    int k = blockIdx.x, j = threadIdx.x;
    float a2 = 0.f, a3 = 0.f;
    for (int t = 0; t < D; ++t) {
        a2 += W2[k*D + t] * Wl[t*D + j];
        a3 += W3[k*D + t] * Wl[(D + t)*D + j];
    }
    M2[k*D + j] = a2;
    M3[k*D + j] = a3;
}

__device__ __forceinline__ float lane_bcast(float v, int k) {
    return __uint_as_float(__builtin_amdgcn_readlane(__float_as_uint(v), k));
}

__device__ __forceinline__ float wave_l2norm(float v) {
    float ss = v * v;
    #pragma unroll
    for (int off = 32; off; off >>= 1) ss += __shfl_xor(ss, off);
    return sqrtf(ss);
}

// ---------------------------------------------------------------------------
// h0 = l2norm(relu(X @ W1)) for nodes (rows < N_NODES) and batch seeds.
// one wave per row, lane = output dim (D_IN = 2 hard-coded)
// ---------------------------------------------------------------------------
__global__ void __launch_bounds__(256) k_init(const float* __restrict__ X,
                                              const float* __restrict__ Xs,
                                              const float* __restrict__ W1,
                                              float* __restrict__ H,
                                              float* __restrict__ HS) {
    int row = blockIdx.x * (blockDim.x >> 6) + (threadIdx.x >> 6);
    int j   = threadIdx.x & 63;
    if (row >= N_NODES + BATCH) return;
    float x0, x1; float* out;
    if (row < N_NODES) {
        x0 = X[row*2]; x1 = X[row*2 + 1]; out = H + (size_t)row * D;
    } else {
        int r = row - N_NODES;
        x0 = Xs[r*2]; x1 = Xs[r*2 + 1]; out = HS + (size_t)r * D;
    }
    float v = fmaxf(fmaf(x0, W1[j], x1 * W1[D + j]), 0.f);
    float n = wave_l2norm(v);
    out[j] = v / fmaxf(n, EPS);
}

// ---------------------------------------------------------------------------
// SPMM: h_nv[r] = sum over edges with edge_row==r of H[edge_col[e]]
// one wave per row (rows owned exclusively -> no atomics), lane = dim
// ---------------------------------------------------------------------------
__global__ void __launch_bounds__(256) k_spmm(const int* __restrict__ edge_col,
                                              const int* __restrict__ row_start,
                                              const float* __restrict__ H,
                                              float* __restrict__ HNV) {
    int row = blockIdx.x * (blockDim.x >> 6) + (threadIdx.x >> 6);
    if (row >= N_NODES) return;
    int j = threadIdx.x & 63;
    int s = row_start[row], e = row_start[row + 1];
    float acc = 0.f;
    int i = s;
    for (; i + 1 < e; i += 2) {
        int c0 = edge_col[i];
        int c1 = edge_col[i + 1];
        float v0 = H[(size_t)c0 * D + j];
        float v1 = H[(size_t)c1 * D + j];
        acc += v0; acc += v1;
    }
    if (i < e) acc += H[(size_t)edge_col[i] * D + j];
    HNV[(size_t)row * D + j] = acc;
}

// ---------------------------------------------------------------------------
// Batch pool: HNVS[b] += sum_{batch_assign[n]==b} H[n]
// LDS 64x64 accumulator per block, global atomics at the end.
// ---------------------------------------------------------------------------
__global__ void __launch_bounds__(256) k_pool(const int* __restrict__ batch_assign,
                                              const float* __restrict__ H,
                                              float* __restrict__ HNVS) {
    __shared__ float acc[BATCH * D];
    int t = threadIdx.x;
    for (int i = t; i < BATCH * D; i += blockDim.x) acc[i] = 0.f;
    __syncthreads();
    int lane   = t & 63;
    int wave   = blockIdx.x * (blockDim.x >> 6) + (t >> 6);
    int nwaves = gridDim.x * (blockDim.x >> 6);
    for (int n = wave; n < N_NODES; n += nwaves) {
        int b = batch_assign[n];
        atomicAdd(&acc[b * D + lane], H[(size_t)n * D + lane]);
    }
    __syncthreads();
    for (int i = t; i < BATCH * D; i += blockDim.x) atomicAdd(&HNVS[i], acc[i]);
}

// ---------------------------------------------------------------------------
// Dense update: Hout[r] = l2norm(relu(Hin[r]@M2 + HNV[r]@M3 + bl))
// one wave per row; M2/M3 staged in LDS; h values broadcast via readlane.
// ---------------------------------------------------------------------------
__global__ void __launch_bounds__(256) k_update(const float* __restrict__ Hin,
                                                const float* __restrict__ HNV,
                                                const float* __restrict__ M2,
                                                const float* __restrict__ M3,
                                                const float* __restrict__ bl,
                                                float* __restrict__ Hout, int nrows) {
    __shared__ float sM2[D * D];
    __shared__ float sM3[D * D];
    int t = threadIdx.x;
    for (int i = t; i < D * D; i += blockDim.x) { sM2[i] = M2[i]; sM3[i] = M3[i]; }
    __syncthreads();
    int row = blockIdx.x * (blockDim.x >> 6) + (t >> 6);
    if (row >= nrows) return;
    int j = t & 63;
    float hv = Hin[(size_t)row * D + j];
    float gv = HNV[(size_t)row * D + j];
    float a = bl[j];
    #pragma unroll
    for (int k = 0; k < D; ++k) {
        float hk = lane_bcast(hv, k);
        float gk = lane_bcast(gv, k);
        a = fmaf(hk, sM2[k * D + j], a);
        a = fmaf(gk, sM3[k * D + j], a);
    }
    float v = fmaxf(a, 0.f);
    float n = wave_l2norm(v);
    Hout[(size_t)row * D + j] = v / fmaxf(n, EPS);
}

// ---------------------------------------------------------------------------
extern "C" void kernel_launch(void* const* d_in, const int* in_sizes, int n_in,
                              void* d_out, int out_size, void* d_ws, size_t ws_size,
                              hipStream_t stream) {
    const int*   edge_row = (const int*)  d_in[0];
    const int*   edge_col = (const int*)  d_in[1];
    const int*   batch    = (const int*)  d_in[2];
    const float* X        = (const float*)d_in[3];
    const float* Xs       = (const float*)d_in[4];
    const float* W1       = (const float*)d_in[5];
    const float* W2       = (const float*)d_in[6];
    const float* W3       = (const float*)d_in[7];
    const float* Wl       = (const float*)d_in[8];
    const float* bl       = (const float*)d_in[9];
    // depth is fixed at 3 in setup_inputs(); hard-coded below.

    // h and hs live directly in d_out: [N_NODES*D | BATCH*D]
    float* H  = (float*)d_out;
    float* HS = (float*)d_out + (size_t)N_NODES * D;

    // workspace layout
    float* HNV  = (float*)d_ws;                       // N_NODES*D
    float* HNVS = HNV + (size_t)N_NODES * D;          // BATCH*D
    float* M2   = HNVS + BATCH * D;                   // D*D
    float* M3   = M2 + D * D;                         // D*D
    int*   row_start = (int*)(M3 + D * D);            // N_NODES+1

    k_rowstart<<<(N_NODES + 256) / 256, 256, 0, stream>>>(edge_row, row_start);
    k_fuse<<<D, D, 0, stream>>>(W2, W3, Wl, M2, M3);
    k_init<<<(N_NODES + BATCH + 3) / 4, 256, 0, stream>>>(X, Xs, W1, H, HS);

    const int spmm_blocks = (N_NODES + 3) / 4;
    for (int it = 0; it < 3; ++it) {
        k_spmm<<<spmm_blocks, 256, 0, stream>>>(edge_col, row_start, H, HNV);
        hipMemsetAsync(HNVS, 0, BATCH * D * sizeof(float), stream);
        k_pool<<<128, 256, 0, stream>>>(batch, H, HNVS);
        k_update<<<spmm_blocks, 256, 0, stream>>>(H, HNV, M2, M3, bl, H, N_NODES);
        k_update<<<(BATCH + 3) / 4, 256, 0, stream>>>(HS, HNVS, M2, M3, bl, HS, BATCH);
    }
}

// Round 2
// 433.576 us; speedup vs baseline: 1.3995x; 1.3995x over previous
//
#include <hip/hip_runtime.h>
#include <math.h>

#define N_NODES 50000
#define N_EDGES 1200000
#define BATCH   64
#define D       64
#define EPS     1e-12f

// ---------------------------------------------------------------------------
// CSR row offsets from sorted edge_row: row_start[r] = lower_bound(edge_row, r)
// ---------------------------------------------------------------------------
__global__ void k_rowstart(const int* __restrict__ edge_row, int* __restrict__ row_start) {
    int r = blockIdx.x * blockDim.x + threadIdx.x;
    if (r > N_NODES) return;
    int lo = 0, hi = N_EDGES;
    while (lo < hi) {
        int mid = (lo + hi) >> 1;
        if (edge_row[mid] < r) lo = mid + 1; else hi = mid;
    }
    row_start[r] = lo;
}

// ---------------------------------------------------------------------------
// Fused weights: M2 = W2 @ Wl[:64,:], M3 = W3 @ Wl[64:,:]
// ---------------------------------------------------------------------------
__global__ void k_fuse(const float* __restrict__ W2, const float* __restrict__ W3,
                       const float* __restrict__ Wl,
                       float* __restrict__ M2, float* __restrict__ M3) {
    int k = blockIdx.x, j = threadIdx.x;
    float a2 = 0.f, a3 = 0.f;
    for (int t = 0; t < D; ++t) {
        a2 += W2[k*D + t] * Wl[t*D + j];
        a3 += W3[k*D + t] * Wl[(D + t)*D + j];
    }
    M2[k*D + j] = a2;
    M3[k*D + j] = a3;
}

__device__ __forceinline__ float lane_bcast(float v, int k) {
    return __uint_as_float(__builtin_amdgcn_readlane(__float_as_uint(v), k));
}

__device__ __forceinline__ float wave_l2norm(float v) {
    float ss = v * v;
    #pragma unroll
    for (int off = 32; off; off >>= 1) ss += __shfl_xor(ss, off);
    return sqrtf(ss);
}

// ---------------------------------------------------------------------------
// h0 = l2norm(relu(X @ W1)); nodes -> B0 (ws), batch seeds -> HS (d_out)
// ---------------------------------------------------------------------------
__global__ void __launch_bounds__(256) k_init(const float* __restrict__ X,
                                              const float* __restrict__ Xs,
                                              const float* __restrict__ W1,
                                              float* __restrict__ B0,
                                              float* __restrict__ HS) {
    int row = blockIdx.x * 4 + (threadIdx.x >> 6);
    int j   = threadIdx.x & 63;
    if (row >= N_NODES + BATCH) return;
    float x0, x1; float* out;
    if (row < N_NODES) {
        x0 = X[row*2]; x1 = X[row*2 + 1]; out = B0 + (size_t)row * D;
    } else {
        int r = row - N_NODES;
        x0 = Xs[r*2]; x1 = Xs[r*2 + 1]; out = HS + (size_t)r * D;
    }
    float v = fmaxf(fmaf(x0, W1[j], x1 * W1[D + j]), 0.f);
    float n = wave_l2norm(v);
    out[j] = v / fmaxf(n, EPS);
}

// ---------------------------------------------------------------------------
// Fused iteration (nodes): hnv = gather-sum; Hn[r] = l2norm(relu(h@M2 + hnv@M3 + bl))
// one wave per row; 8-deep gather unroll for MLP; M2/M3 staged in LDS.
// ---------------------------------------------------------------------------
__global__ void __launch_bounds__(256, 5) k_iter(const int* __restrict__ edge_col,
                                                 const int* __restrict__ row_start,
                                                 const float* __restrict__ Hc,
                                                 float* __restrict__ Hn,
                                                 const float* __restrict__ M2,
                                                 const float* __restrict__ M3,
                                                 const float* __restrict__ bl) {
    __shared__ float sM2[D * D];
    __shared__ float sM3[D * D];
    int t = threadIdx.x;
    for (int i = t; i < D * D; i += 256) { sM2[i] = M2[i]; sM3[i] = M3[i]; }
    __syncthreads();
    int row = blockIdx.x * 4 + (t >> 6);
    if (row >= N_NODES) return;
    int j = t & 63;

    int s = __builtin_amdgcn_readfirstlane(row_start[row]);
    int e = __builtin_amdgcn_readfirstlane(row_start[row + 1]);

    float acc0 = 0.f, acc1 = 0.f;
    int i = s;
    for (; i + 8 <= e; i += 8) {
        int c0 = edge_col[i + 0], c1 = edge_col[i + 1];
        int c2 = edge_col[i + 2], c3 = edge_col[i + 3];
        int c4 = edge_col[i + 4], c5 = edge_col[i + 5];
        int c6 = edge_col[i + 6], c7 = edge_col[i + 7];
        float v0 = Hc[c0 * D + j], v1 = Hc[c1 * D + j];
        float v2 = Hc[c2 * D + j], v3 = Hc[c3 * D + j];
        float v4 = Hc[c4 * D + j], v5 = Hc[c5 * D + j];
        float v6 = Hc[c6 * D + j], v7 = Hc[c7 * D + j];
        acc0 += (v0 + v2) + (v4 + v6);
        acc1 += (v1 + v3) + (v5 + v7);
    }
    for (; i < e; ++i) acc0 += Hc[edge_col[i] * D + j];
    float gv = acc0 + acc1;

    float hv = Hc[(size_t)row * D + j];
    float a2 = 0.f, a3 = bl[j];
    #pragma unroll
    for (int k = 0; k < D; ++k) {
        float hk = lane_bcast(hv, k);
        float gk = lane_bcast(gv, k);
        a2 = fmaf(hk, sM2[k * D + j], a2);
        a3 = fmaf(gk, sM3[k * D + j], a3);
    }
    float v = fmaxf(a2 + a3, 0.f);
    float n = wave_l2norm(v);
    Hn[(size_t)row * D + j] = v / fmaxf(n, EPS);
}

// ---------------------------------------------------------------------------
// Batch pool: HNVS[b] += sum_{batch_assign[n]==b} H[n]
// ---------------------------------------------------------------------------
__global__ void __launch_bounds__(256) k_pool(const int* __restrict__ batch_assign,
                                              const float* __restrict__ H,
                                              float* __restrict__ HNVS) {
    __shared__ float acc[BATCH * D];
    int t = threadIdx.x;
    for (int i = t; i < BATCH * D; i += 256) acc[i] = 0.f;
    __syncthreads();
    int lane   = t & 63;
    int wave   = blockIdx.x * 4 + (t >> 6);
    int nwaves = gridDim.x * 4;
    for (int n = wave; n < N_NODES; n += nwaves) {
        int b = batch_assign[n];
        atomicAdd(&acc[b * D + lane], H[(size_t)n * D + lane]);
    }
    __syncthreads();
    for (int i = t; i < BATCH * D; i += 256) atomicAdd(&HNVS[i], acc[i]);
}

// ---------------------------------------------------------------------------
// hs update (64 rows, in place) + zero HNVS for the next pool.
// ---------------------------------------------------------------------------
__global__ void __launch_bounds__(256) k_hs(float* __restrict__ HS,
                                            float* __restrict__ HNVS,
                                            const float* __restrict__ M2,
                                            const float* __restrict__ M3,
                                            const float* __restrict__ bl) {
    __shared__ float sM2[D * D];
    __shared__ float sM3[D * D];
    int t = threadIdx.x;
    for (int i = t; i < D * D; i += 256) { sM2[i] = M2[i]; sM3[i] = M3[i]; }
    __syncthreads();
    int row = blockIdx.x * 4 + (t >> 6);
    if (row >= BATCH) return;
    int j = t & 63;
    float hv = HS[(size_t)row * D + j];
    float gv = HNVS[row * D + j];
    HNVS[row * D + j] = 0.f;   // re-init for the next pool (stream-ordered)
    float a2 = 0.f, a3 = bl[j];
    #pragma unroll
    for (int k = 0; k < D; ++k) {
        float hk = lane_bcast(hv, k);
        float gk = lane_bcast(gv, k);
        a2 = fmaf(hk, sM2[k * D + j], a2);
        a3 = fmaf(gk, sM3[k * D + j], a3);
    }
    float v = fmaxf(a2 + a3, 0.f);
    float n = wave_l2norm(v);
    HS[(size_t)row * D + j] = v / fmaxf(n, EPS);
}

// ---------------------------------------------------------------------------
extern "C" void kernel_launch(void* const* d_in, const int* in_sizes, int n_in,
                              void* d_out, int out_size, void* d_ws, size_t ws_size,
                              hipStream_t stream) {
    const int*   edge_row = (const int*)  d_in[0];
    const int*   edge_col = (const int*)  d_in[1];
    const int*   batch    = (const int*)  d_in[2];
    const float* X        = (const float*)d_in[3];
    const float* Xs       = (const float*)d_in[4];
    const float* W1       = (const float*)d_in[5];
    const float* W2       = (const float*)d_in[6];
    const float* W3       = (const float*)d_in[7];
    const float* Wl       = (const float*)d_in[8];
    const float* bl       = (const float*)d_in[9];

    float* H  = (float*)d_out;                        // final node embeddings
    float* HS = (float*)d_out + (size_t)N_NODES * D;  // hs (updated in place)

    // workspace: B0, B1 ping-pong node buffers + HNVS + M2/M3 + row_start
    float* B0   = (float*)d_ws;                       // N_NODES*D
    float* B1   = B0 + (size_t)N_NODES * D;           // N_NODES*D
    float* HNVS = B1 + (size_t)N_NODES * D;           // BATCH*D
    float* M2   = HNVS + BATCH * D;                   // D*D
    float* M3   = M2 + D * D;                         // D*D
    int*   row_start = (int*)(M3 + D * D);            // N_NODES+1

    const int nblk = (N_NODES + 3) / 4;

    k_rowstart<<<(N_NODES + 256) / 256, 256, 0, stream>>>(edge_row, row_start);
    k_fuse<<<D, D, 0, stream>>>(W2, W3, Wl, M2, M3);
    k_init<<<(N_NODES + BATCH + 3) / 4, 256, 0, stream>>>(X, Xs, W1, B0, HS);

    hipMemsetAsync(HNVS, 0, BATCH * D * sizeof(float), stream);
    k_pool<<<256, 256, 0, stream>>>(batch, B0, HNVS);

    // iter 1: B0 -> B1
    k_iter<<<nblk, 256, 0, stream>>>(edge_col, row_start, B0, B1, M2, M3, bl);
    k_hs<<<16, 256, 0, stream>>>(HS, HNVS, M2, M3, bl);
    k_pool<<<256, 256, 0, stream>>>(batch, B1, HNVS);

    // iter 2: B1 -> B0
    k_iter<<<nblk, 256, 0, stream>>>(edge_col, row_start, B1, B0, M2, M3, bl);
    k_hs<<<16, 256, 0, stream>>>(HS, HNVS, M2, M3, bl);
    k_pool<<<256, 256, 0, stream>>>(batch, B0, HNVS);

    // iter 3: B0 -> H (d_out)
    k_iter<<<nblk, 256, 0, stream>>>(edge_col, row_start, B0, H, M2, M3, bl);
    k_hs<<<16, 256, 0, stream>>>(HS, HNVS, M2, M3, bl);
}